// Round 4
// baseline (1249.231 us; speedup 1.0000x reference)
//
#include <hip/hip_runtime.h>
#include <hip/hip_bf16.h>

typedef unsigned short u16t;

__device__ __forceinline__ float bfu(u16t u) {
    union { unsigned int i; float f; } c;
    c.i = ((unsigned int)u) << 16;
    return c.f;
}
__device__ __forceinline__ u16t fbf(float f) {
    __hip_bfloat16 h = __float2bfloat16(f);
    return *reinterpret_cast<u16t*>(&h);
}

// ---------------------------------------------------------------------------
// Fused BN + LeakyReLU + 3x3 conv.  All fp32.  src0 = x (64ch);
// src1/src2 = fp32 ws intermediates (32ch each). C_IN in {64,96,128}.
// ---------------------------------------------------------------------------
template<int C_IN, int C_OUT>
__global__ __launch_bounds__(256) void bn_conv3x3_k(
    const float* __restrict__ src0, const float* __restrict__ src1,
    const float* __restrict__ src2,
    const float* __restrict__ gg, const float* __restrict__ bb,
    const float* __restrict__ mm, const float* __restrict__ vv,
    const float* __restrict__ w,  const float* __restrict__ wb,
    float* __restrict__ dst)
{
    constexpr int F = 64, T = 512, TT = 32;
    constexpr int LW = TT + 2;          // 34 valid columns
    constexpr int PITCH = 36;           // float4-aligned row pitch
    constexpr int GROUPS = 256 / C_OUT; // 8 (C_OUT=32) or 4 (C_OUT=64)
    constexpr int NT = TT / GROUPS;     // 4 or 8 outputs per thread

    __shared__ float s_in[C_IN][3][PITCH];
    __shared__ float s_sc[C_IN], s_sh[C_IN];

    const int tid = threadIdx.x;
    const int t0 = blockIdx.x * TT;
    const int f  = blockIdx.y;
    const int b  = blockIdx.z;

    if (tid < C_IN) {
        float sc = gg[tid] * rsqrtf(vv[tid] + 1e-5f);
        s_sc[tid] = sc;
        s_sh[tid] = bb[tid] - mm[tid] * sc;
    }
    __syncthreads();

    for (int idx = tid; idx < C_IN * 3 * LW; idx += 256) {
        int c  = idx / (3 * LW);
        int r  = idx - c * (3 * LW);
        int kh = r / LW;
        int tt = r - kh * LW;
        int fi = f + kh - 1;
        int ti = t0 + tt - 1;
        float val = 0.f;
        if ((unsigned)fi < (unsigned)F && (unsigned)ti < (unsigned)T) {
            float xv;
            if (c < 64) {
                xv = src0[(((long)b * 64 + c) * F + fi) * T + ti];
            } else if (C_IN > 96 && c >= 96) {
                xv = src2[(((long)b * 32 + (c - 96)) * F + fi) * T + ti];
            } else {
                xv = src1[(((long)b * 32 + (c - 64)) * F + fi) * T + ti];
            }
            float xn = xv * s_sc[c] + s_sh[c];
            val = (xn >= 0.f) ? xn : 0.01f * xn;
        }
        s_in[c][kh][tt] = val;
    }
    __syncthreads();

    const int co = tid / GROUPS;
    const int g  = tid % GROUPS;
    const int tb = g * NT;

    float acc[NT];
#pragma unroll
    for (int i = 0; i < NT; i++) acc[i] = 0.f;

    for (int c = 0; c < C_IN; c++) {
#pragma unroll
        for (int kh = 0; kh < 3; kh++) {
            const float* row = &s_in[c][kh][tb];
            float vreg[NT + 2];
#pragma unroll
            for (int i = 0; i < NT; i += 4) {
                float4 q4 = *(const float4*)(row + i);
                vreg[i] = q4.x; vreg[i+1] = q4.y; vreg[i+2] = q4.z; vreg[i+3] = q4.w;
            }
            vreg[NT]     = row[NT];
            vreg[NT + 1] = row[NT + 1];
            const float* wp = &w[((co * C_IN + c) * 3 + kh) * 3];
            float w0 = wp[0], w1 = wp[1], w2 = wp[2];
#pragma unroll
            for (int i = 0; i < NT; i++)
                acc[i] += vreg[i] * w0 + vreg[i+1] * w1 + vreg[i+2] * w2;
        }
    }
    const float bias = wb[co];
#pragma unroll
    for (int i = 0; i < NT; i++) {
        int t = t0 + tb + i;
        dst[(((long)b * C_OUT + co) * F + f) * T + t] = acc[i] + bias;
    }
}

// ---------------------------------------------------------------------------
// Fused qkv-projection + banded local attention.  One block per (h,f,b),
// 512 threads = query positions.  K in fp32 LDS, V in bf16 LDS, both
// transposed [d][t] so inner-loop reads are stride-1 (conflict-free).
// Phantom zero-keys for t<64: init m=0, l=64-t.
// ---------------------------------------------------------------------------
__global__ __launch_bounds__(512) void attn_fused_k(
    const float* __restrict__ y, const float* __restrict__ qw,
    const float* __restrict__ qb, float* __restrict__ o)
{
    constexpr int F = 64, T = 512;
    const int h = blockIdx.x, f = blockIdx.y, b = blockIdx.z;
    const int t = threadIdx.x;

    __shared__ float s_wT[64][48];              // [c][kind*16+d]
    __shared__ float s_b[48];
    __shared__ float s_kT[16][T + 8];           // transposed, stride-1 reads
    __shared__ u16t  s_vT[16][T + 8];

    for (int i = t; i < 64 * 48; i += 512) {
        int c = i / 48, r = i - c * 48;
        int kind = r >> 4, d = r & 15;
        s_wT[c][r] = qw[(kind * 64 + h * 16 + d) * 64 + c];
    }
    if (t < 48) {
        int kind = t >> 4, d = t & 15;
        s_b[t] = qb[kind * 64 + h * 16 + d];
    }
    __syncthreads();

    // qkv projection for position t: 48 accumulators (q,k,v x 16 dims)
    float acc[48];
#pragma unroll
    for (int r = 0; r < 48; r++) acc[r] = s_b[r];

    const long chs = (long)F * T;
    const long ybase = (long)b * 64 * chs + (long)f * T + t;
    for (int c = 0; c < 64; c++) {
        float yv = y[ybase + (long)c * chs];
        const float4* wrow = (const float4*)(&s_wT[c][0]);
#pragma unroll
        for (int r4 = 0; r4 < 12; r4++) {
            float4 w4 = wrow[r4];
            acc[r4*4+0] += w4.x * yv;
            acc[r4*4+1] += w4.y * yv;
            acc[r4*4+2] += w4.z * yv;
            acc[r4*4+3] += w4.w * yv;
        }
    }
#pragma unroll
    for (int d = 0; d < 16; d++) {
        s_kT[d][t] = acc[16 + d];
        s_vT[d][t] = fbf(acc[32 + d]);
    }
    float q[16];
#pragma unroll
    for (int d = 0; d < 16; d++) q[d] = 0.25f * acc[d];  // fold 1/sqrt(16)
    __syncthreads();

    const int n_neg = (t < 64) ? (64 - t) : 0;
    float m = (n_neg > 0) ? 0.f : -3.0e38f;
    float l = (float)n_neg;
    float oa[16];
#pragma unroll
    for (int d = 0; d < 16; d++) oa[d] = 0.f;

    const int p0 = (t >= 64) ? (t - 64) : 0;
    const int p1 = (t + 64 <= T - 1) ? (t + 64) : (T - 1);

    for (int p = p0; p <= p1; p++) {
        float s = 0.f;
#pragma unroll
        for (int d = 0; d < 16; d++) s += q[d] * s_kT[d][p];

        float mn = fmaxf(m, s);
        float em = __expf(m - mn);
        float es = __expf(s - mn);
        l = l * em + es;
#pragma unroll
        for (int d = 0; d < 16; d++)
            oa[d] = oa[d] * em + es * bfu(s_vT[d][p]);
        m = mn;
    }
    const float inv = 1.0f / l;
#pragma unroll
    for (int d = 0; d < 16; d++)
        o[(((long)b * 64 + h * 16 + d) * F + f) * T + t] = oa[d] * inv;
}

// ---------------------------------------------------------------------------
// Fused o-projection + BN + LeakyReLU + final conv1x1.  All fp32.
// ---------------------------------------------------------------------------
__global__ __launch_bounds__(256) void oproj_final_k(
    const float* __restrict__ ob, const float* __restrict__ y,
    const float* __restrict__ ow, const float* __restrict__ obias,
    const float* __restrict__ sg, const float* __restrict__ sb,
    const float* __restrict__ sm, const float* __restrict__ sv,
    const float* __restrict__ sw, const float* __restrict__ swb,
    float* __restrict__ out)
{
    constexpr int F = 64, T = 512;
    __shared__ float s_ob[64][64];
    __shared__ float s_y2[64][64];   // bn_lrelu'd y half
    __shared__ float s_att[64][64];  // bn_lrelu'd att half
    __shared__ float s_sc[128], s_sh[128];

    const int tid = threadIdx.x;
    const int t0 = blockIdx.x * 64;
    const int f = blockIdx.y, b = blockIdx.z;

    if (tid < 128) {
        float sc = sg[tid] * rsqrtf(sv[tid] + 1e-5f);
        s_sc[tid] = sc;
        s_sh[tid] = sb[tid] - sm[tid] * sc;
    }
    __syncthreads();

    for (int i = tid; i < 64 * 64; i += 256) {
        int c = i >> 6, tt = i & 63;
        long gi = (((long)b * 64 + c) * F + f) * T + t0 + tt;
        s_ob[c][tt] = ob[gi];
        float yv = y[gi];
        float xn = yv * s_sc[c] + s_sh[c];
        s_y2[c][tt] = (xn >= 0.f) ? xn : 0.01f * xn;
    }
    __syncthreads();

    const int t  = tid & 63;
    const int wv = tid >> 6;       // 4 groups x 16 out-channels

    float acc[16];
#pragma unroll
    for (int i = 0; i < 16; i++) acc[i] = obias[wv * 16 + i];
    for (int c = 0; c < 64; c++) {
        float v = s_ob[c][t];
#pragma unroll
        for (int i = 0; i < 16; i++)
            acc[i] += ow[(wv * 16 + i) * 64 + c] * v;
    }
#pragma unroll
    for (int i = 0; i < 16; i++) {
        int oc = wv * 16 + i;
        float xn = acc[i] * s_sc[64 + oc] + s_sh[64 + oc];
        s_att[oc][t] = (xn >= 0.f) ? xn : 0.01f * xn;
    }
    __syncthreads();

    float acc2[16];
#pragma unroll
    for (int i = 0; i < 16; i++) acc2[i] = swb[wv * 16 + i];
    for (int c = 0; c < 64; c++) {
        float v0 = s_y2[c][t];
        float v1 = s_att[c][t];
#pragma unroll
        for (int i = 0; i < 16; i++) {
            const float* wr = &sw[(wv * 16 + i) * 128];
            acc2[i] += wr[c] * v0 + wr[64 + c] * v1;
        }
    }
#pragma unroll
    for (int i = 0; i < 16; i++)
        out[(((long)b * 64 + wv * 16 + i) * F + f) * T + t0 + t] = acc2[i];
}

// ---------------------------------------------------------------------------
extern "C" void kernel_launch(void* const* d_in, const int* in_sizes, int n_in,
                              void* d_out, int out_size, void* d_ws, size_t ws_size,
                              hipStream_t stream)
{
    (void)in_sizes; (void)n_in; (void)out_size; (void)ws_size;

    const float* x      = (const float*)d_in[0];
    const float* bd0_g  = (const float*)d_in[1];
    const float* bd0_b  = (const float*)d_in[2];
    const float* bd0_m  = (const float*)d_in[3];
    const float* bd0_v  = (const float*)d_in[4];
    const float* bd0_w  = (const float*)d_in[5];
    const float* bd0_wb = (const float*)d_in[6];
    const float* bd1_g  = (const float*)d_in[7];
    const float* bd1_b  = (const float*)d_in[8];
    const float* bd1_m  = (const float*)d_in[9];
    const float* bd1_v  = (const float*)d_in[10];
    const float* bd1_w  = (const float*)d_in[11];
    const float* bd1_wb = (const float*)d_in[12];
    const float* bdo_g  = (const float*)d_in[13];
    const float* bdo_b  = (const float*)d_in[14];
    const float* bdo_m  = (const float*)d_in[15];
    const float* bdo_v  = (const float*)d_in[16];
    const float* bdo_w  = (const float*)d_in[17];
    const float* bdo_wb = (const float*)d_in[18];
    const float* qkv_w  = (const float*)d_in[19];
    const float* qkv_b  = (const float*)d_in[20];
    const float* o_w    = (const float*)d_in[21];
    const float* o_b    = (const float*)d_in[22];
    const float* sao_g  = (const float*)d_in[23];
    const float* sao_b  = (const float*)d_in[24];
    const float* sao_m  = (const float*)d_in[25];
    const float* sao_v  = (const float*)d_in[26];
    const float* sao_w  = (const float*)d_in[27];
    const float* sao_wb = (const float*)d_in[28];

    char* ws = (char*)d_ws;
    // fp32 intermediates, peak 67.1 MB (ws >= 84MB proven by rounds 2/3):
    //   [0, 16.8M)    a0   (later reused by ob)
    //   [16.8, 33.6M) a1   (later reused by ob)
    //   [33.6, 67.1M) y
    float* a0  = (float*)(ws);
    float* a1  = (float*)(ws + 16777216);
    float* y   = (float*)(ws + 33554432);
    float* ob  = (float*)(ws);            // 33.6M, over a0+a1 (dead after y)

    dim3 blk(256);
    dim3 g3(16, 64, 4);   // T/32, F, B

    hipLaunchKernelGGL((bn_conv3x3_k<64, 32>), g3, blk, 0, stream,
        x, nullptr, nullptr, bd0_g, bd0_b, bd0_m, bd0_v, bd0_w, bd0_wb, a0);
    hipLaunchKernelGGL((bn_conv3x3_k<96, 32>), g3, blk, 0, stream,
        x, a0, nullptr, bd1_g, bd1_b, bd1_m, bd1_v, bd1_w, bd1_wb, a1);
    hipLaunchKernelGGL((bn_conv3x3_k<128, 64>), g3, blk, 0, stream,
        x, a0, a1, bdo_g, bdo_b, bdo_m, bdo_v, bdo_w, bdo_wb, y);
    hipLaunchKernelGGL(attn_fused_k, dim3(4, 64, 4), dim3(512), 0, stream,
        y, qkv_w, qkv_b, ob);
    hipLaunchKernelGGL(oproj_final_k, dim3(8, 64, 4), blk, 0, stream,
        ob, y, o_w, o_b, sao_g, sao_b, sao_m, sao_v, sao_w, sao_wb,
        (float*)d_out);
}